// Round 17
// baseline (152.355 us; speedup 1.0000x reference)
//
#include <hip/hip_runtime.h>

#define NWIN 640
#define ZHW  144
#define DIM  192
#define HEADS 6
#define DH   32
#define TW   64
// RSCALE * log2(e): folded into q-projection weights/bias
#define C_FOLD 0.25503450f
#define LOG2E 1.4426950408889634f

typedef float f32x4 __attribute__((ext_vector_type(4)));
typedef __bf16 bf16x8 __attribute__((ext_vector_type(8)));

__device__ __forceinline__ unsigned short f2b(float f) {
  unsigned u = __float_as_uint(f);
  u += 0x7fffu + ((u >> 16) & 1u);
  return (unsigned short)(u >> 16);
}
__device__ __forceinline__ unsigned short cvtb(float f) {
  return __builtin_bit_cast(unsigned short, (__bf16)f);
}
__device__ __forceinline__ uint2 pack4(f32x4 a) {
  uint2 r;
  r.x = (unsigned)cvtb(a[0]) | ((unsigned)cvtb(a[1]) << 16);
  r.y = (unsigned)cvtb(a[2]) | ((unsigned)cvtb(a[3]) << 16);
  return r;
}

// A/B fragment for mfma_f32_16x16x32_bf16 from a row-major array:
// lane reads elements k0..k0+3 and k0+16..k0+19 of its row (k0 = 4*(lane>>4)).
__device__ __forceinline__ bf16x8 ld_frag(const unsigned short* p) {
  uint2 lo = *(const uint2*)(p);
  uint2 hi = *(const uint2*)(p + 16);
  uint4 u; u.x = lo.x; u.y = lo.y; u.z = hi.x; u.w = hi.y;
  return __builtin_bit_cast(bf16x8, u);
}
#define MFMA16(a, b, c) __builtin_amdgcn_mfma_f32_16x16x32_bf16((a), (b), (c), 0, 0, 0)

// ================== megaprep: 4 independent prep jobs, one launch ==========
// LDS 25.1 KB -> 6 blocks/CU; streaming loops fully unrolled (MLP).
// [0,1440)    conv_x  : x f32 -> xb2 bf16 A-frag-packed (64-row tiles)
// [1440,2088) bias    : table gather -> biasz frag-packed (48-wh chunks)
// [2088,2728) mask    : mask f32 -> per-(win,strip,lane) u64 keep-nibbles
// [2728,2782) weights : w1/w2 -> B-frag-packed bf16
#define MP_BIAS0 1440
#define MP_MASK0 2088
#define MP_W0    2728
__global__ __launch_bounds__(256) void megaprep(
    const float* __restrict__ x, const float* __restrict__ mask,
    const float* __restrict__ w1, const float* __restrict__ w2,
    const float* __restrict__ table, const int* __restrict__ pidx,
    unsigned short* __restrict__ xb2, unsigned long long* __restrict__ mq,
    uint4* __restrict__ w1t, uint4* __restrict__ w2t,
    uint2* __restrict__ biasz)
{
  __shared__ __align__(16) unsigned char smem[25088];
  const int tid = threadIdx.x;
  const int b = blockIdx.x;

  if (b < MP_BIAS0) {
    // ---------------- conv_x (64-row tile) ----------------
    unsigned short (*xl)[196] = (unsigned short(*)[196])smem;  // [64][196]
    const int r0 = b * 64;
    const float4* src = (const float4*)(x + (size_t)r0 * DIM);
    float4 v[12];
    #pragma unroll
    for (int u = 0; u < 12; ++u) v[u] = src[tid + 256 * u];
    #pragma unroll
    for (int u = 0; u < 12; ++u) {
      int i = tid + 256 * u;
      int e = i * 4, r = e / DIM, c = e % DIM;
      uint2 pk;
      pk.x = (unsigned)f2b(v[u].x) | ((unsigned)f2b(v[u].y) << 16);
      pk.y = (unsigned)f2b(v[u].z) | ((unsigned)f2b(v[u].w) << 16);
      *(uint2*)(&xl[r][c]) = pk;
    }
    __syncthreads();
    uint4* dst = (uint4*)xb2 + (size_t)b * 1536;
    #pragma unroll
    for (int u = 0; u < 6; ++u) {
      int o = tid + 256 * u;
      int rt = o / 384, rem = o - rt * 384, kk = rem >> 6, ln = rem & 63;
      const unsigned short* p = &xl[16 * rt + (ln & 15)][32 * kk + 4 * (ln >> 4)];
      uint2 lo = *(const uint2*)p;
      uint2 hi = *(const uint2*)(p + 16);
      uint4 u4; u4.x = lo.x; u4.y = lo.y; u4.z = hi.x; u4.w = hi.y;
      dst[o] = u4;
    }
  } else if (b < MP_MASK0) {
    // ---------------- bias direct to biasz (48-wh chunk) ----------------
    unsigned short (*tile)[49] = (unsigned short(*)[49])smem;  // [256][49]
    const int b2 = b - MP_BIAS0;
    const int whc = b2 & 7, rem2 = b2 >> 3;       // 648 = 81 * 8
    const int s = rem2 / 9, kst = rem2 - 9 * (rem2 / 9);
    int rowi[12];
    #pragma unroll
    for (int u = 0; u < 12; ++u) {
      int idx = tid + 256 * u;
      int pos = idx / 12;
      int q = 16 * s + (pos >> 4), kk = 16 * kst + (pos & 15);
      rowi[u] = pidx[q * ZHW + kk];
    }
    float4 v[12];
    #pragma unroll
    for (int u = 0; u < 12; ++u) {
      int idx = tid + 256 * u;
      int pos = idx / 12, t = idx - pos * 12;
      v[u] = *(const float4*)(table + (size_t)rowi[u] * 384 + whc * 48 + t * 4);
    }
    #pragma unroll
    for (int u = 0; u < 12; ++u) {
      int idx = tid + 256 * u;
      int pos = idx / 12, t = idx - pos * 12;
      tile[pos][t * 4 + 0] = f2b(v[u].x * LOG2E);
      tile[pos][t * 4 + 1] = f2b(v[u].y * LOG2E);
      tile[pos][t * 4 + 2] = f2b(v[u].z * LOG2E);
      tile[pos][t * 4 + 3] = f2b(v[u].w * LOG2E);
    }
    __syncthreads();
    #pragma unroll
    for (int u = 0; u < 12; ++u) {
      int o = tid + 256 * u;
      int wh = o >> 6, lane = o & 63;
      int lp = (lane & 15) * 16 + 4 * (lane >> 4);
      uint2 uu;
      uu.x = (unsigned)tile[lp + 0][wh] | ((unsigned)tile[lp + 1][wh] << 16);
      uu.y = (unsigned)tile[lp + 2][wh] | ((unsigned)tile[lp + 3][wh] << 16);
      biasz[(((size_t)(whc * 48 + wh) * 9 + s) * 9 + kst) * 64 + lane] = uu;
    }
  } else if (b < MP_W0) {
    // ---------------- mask -> keep-nibble u64 ----------------
    unsigned char* ms = (unsigned char*)smem;  // [2592]
    const int win = b - MP_MASK0;
    const float4* src = (const float4*)(mask + (size_t)win * (ZHW * ZHW));
    float4 a[10], c[10];
    #pragma unroll
    for (int u = 0; u < 10; ++u) {
      int i = tid + 256 * u;
      a[u] = src[2 * i];
      c[u] = src[2 * i + 1];
    }
    float4 at, ct;
    if (tid < 32) { at = src[2 * (2560 + tid)]; ct = src[2 * (2560 + tid) + 1]; }
    #pragma unroll
    for (int u = 0; u < 10; ++u) {
      int i = tid + 256 * u;
      unsigned v = (a[u].x == 0.f ? 1u : 0u) | (a[u].y == 0.f ? 2u : 0u) |
                   (a[u].z == 0.f ? 4u : 0u) | (a[u].w == 0.f ? 8u : 0u) |
                   (c[u].x == 0.f ? 16u : 0u) | (c[u].y == 0.f ? 32u : 0u) |
                   (c[u].z == 0.f ? 64u : 0u) | (c[u].w == 0.f ? 128u : 0u);
      ms[i] = (unsigned char)v;
    }
    if (tid < 32) {
      unsigned v = (at.x == 0.f ? 1u : 0u) | (at.y == 0.f ? 2u : 0u) |
                   (at.z == 0.f ? 4u : 0u) | (at.w == 0.f ? 8u : 0u) |
                   (ct.x == 0.f ? 16u : 0u) | (ct.y == 0.f ? 32u : 0u) |
                   (ct.z == 0.f ? 64u : 0u) | (ct.w == 0.f ? 128u : 0u);
      ms[2560 + tid] = (unsigned char)v;
    }
    __syncthreads();
    #pragma unroll
    for (int u = 0; u < 3; ++u) {
      int o = tid + 256 * u;
      if (o < 576) {
        int s = o >> 6, ln = o & 63;
        int qq = 16 * s + (ln & 15), g = ln >> 4;
        int base = qq * 18 + (g >> 1);
        int nsh = 4 * (g & 1);
        unsigned long long mw = 0;
        #pragma unroll
        for (int kst = 0; kst < 9; ++kst) {
          unsigned nib = ((unsigned)ms[base + 2 * kst] >> nsh) & 0xFu;
          mw |= (unsigned long long)nib << (4 * kst);
        }
        mq[(size_t)win * 576 + o] = mw;
      }
    }
  } else {
    // ---------------- weights -> B-frag-packed ----------------
    int t = (b - MP_W0) * 256 + tid;
    if (t < 13824) {
      int lane = t & 63, r = t >> 6;
      int kk = r % 6, ntg = r / 6;
      int n = ntg * 16 + (lane & 15);
      int k0 = kk * 32 + 4 * ((lane >> 4) & 3);
      float sc = (n < 192) ? C_FOLD : 1.0f;
      unsigned short e[8];
      #pragma unroll
      for (int j = 0; j < 4; ++j) e[j]     = f2b(w1[(size_t)(k0 + j) * 576 + n] * sc);
      #pragma unroll
      for (int j = 0; j < 4; ++j) e[4 + j] = f2b(w1[(size_t)(k0 + 16 + j) * 576 + n] * sc);
      uint4 u;
      u.x = (unsigned)e[0] | ((unsigned)e[1] << 16);
      u.y = (unsigned)e[2] | ((unsigned)e[3] << 16);
      u.z = (unsigned)e[4] | ((unsigned)e[5] << 16);
      u.w = (unsigned)e[6] | ((unsigned)e[7] << 16);
      w1t[t] = u;
    }
    if (t < 4608) {
      int lane = t & 63, r = t >> 6;
      int kk = r % 6, ntg = r / 6;
      int n = ntg * 16 + (lane & 15);
      int k0 = kk * 32 + 4 * ((lane >> 4) & 3);
      unsigned short e[8];
      #pragma unroll
      for (int j = 0; j < 4; ++j) e[j]     = f2b(w2[(size_t)(k0 + j) * 192 + n]);
      #pragma unroll
      for (int j = 0; j < 4; ++j) e[4 + j] = f2b(w2[(size_t)(k0 + 16 + j) * 192 + n]);
      uint4 u;
      u.x = (unsigned)e[0] | ((unsigned)e[1] << 16);
      u.y = (unsigned)e[2] | ((unsigned)e[3] << 16);
      u.z = (unsigned)e[4] | ((unsigned)e[5] << 16);
      u.w = (unsigned)e[6] | ((unsigned)e[7] << 16);
      w2t[t] = u;
    }
  }
}

// ===================== QKV projection (tiled GEMM) =========================
// xb2 A-frag-packed; w1t B-frag-packed (uint4/lane); XCD-swizzled grid.
// Outputs: q,k MFMA-frag-packed uint4; v D-frag uint2.
__global__ __launch_bounds__(256) void qkv_kernel(
    const unsigned short* __restrict__ xb2, const float* __restrict__ b1,
    const uint4* __restrict__ w1t, unsigned short* __restrict__ qkvb)
{
  __shared__ __align__(16) uint4 wb4[2304];                 // 36864 B
  __shared__ __align__(16) unsigned short bn[4][2][16][38]; //  9728 B
  const int tid = threadIdx.x, wv = tid >> 6, lane = tid & 63;
  const int l15 = lane & 15, g = lane >> 4;
  // XCD swizzle: each XCD gets 90 contiguous mt's; the 6 same-mt blocks
  // land on one XCD (A-tile L2 reuse). 4320 = 8 XCD * 540.
  const int b = blockIdx.x;
  const int lid = (b & 7) * 540 + (b >> 3);
  const int mt = lid / 6, ch = lid - mt * 6;
  const int r0 = mt * 128;

  {
    const uint4* wsrc = w1t + (size_t)ch * 2304;
    #pragma unroll 1
    for (int i = tid; i < 2304; i += 256) wb4[i] = wsrc[i];
  }
  bf16x8 xa[2][6];
  {
    const uint4* asrc = (const uint4*)xb2;
    const int rt0 = mt * 8 + 2 * wv;
    #pragma unroll
    for (int rt = 0; rt < 2; ++rt)
      #pragma unroll
      for (int kk = 0; kk < 6; ++kk)
        xa[rt][kk] = __builtin_bit_cast(bf16x8,
            asrc[((size_t)(rt0 + rt) * 6 + kk) * 64 + lane]);
  }
  __syncthreads();
  const int mat = ch >> 1;
  const float bscale = (mat == 0) ? C_FOLD : 1.0f;
  #pragma unroll 1
  for (int hh = 0; hh < 3; ++hh) {
    const int h = (ch & 1) * 3 + hh;
    f32x4 acc[2][2];
    {
      float bv0 = b1[ch * 96 + hh * 32 + l15] * bscale;
      float bv1 = b1[ch * 96 + hh * 32 + 16 + l15] * bscale;
      #pragma unroll
      for (int rt = 0; rt < 2; ++rt) {
        acc[rt][0][0] = bv0; acc[rt][0][1] = bv0; acc[rt][0][2] = bv0; acc[rt][0][3] = bv0;
        acc[rt][1][0] = bv1; acc[rt][1][1] = bv1; acc[rt][1][2] = bv1; acc[rt][1][3] = bv1;
      }
    }
    #pragma unroll
    for (int kk = 0; kk < 6; ++kk) {
      bf16x8 b0  = __builtin_bit_cast(bf16x8, wb4[((2 * hh)     * 6 + kk) * 64 + lane]);
      bf16x8 b1f = __builtin_bit_cast(bf16x8, wb4[((2 * hh + 1) * 6 + kk) * 64 + lane]);
      acc[0][0] = MFMA16(xa[0][kk], b0, acc[0][0]);
      acc[0][1] = MFMA16(xa[0][kk], b1f, acc[0][1]);
      acc[1][0] = MFMA16(xa[1][kk], b0, acc[1][0]);
      acc[1][1] = MFMA16(xa[1][kk], b1f, acc[1][1]);
    }
    if (mat < 2) {
      // bounce to LDS (D layout) then read back as frags -> coalesced uint4
      #pragma unroll
      for (int rt = 0; rt < 2; ++rt)
        #pragma unroll
        for (int ct = 0; ct < 2; ++ct)
          #pragma unroll
          for (int j = 0; j < 4; ++j)
            bn[wv][rt][4 * g + j][16 * ct + l15] = cvtb(acc[rt][ct][j]);
      __builtin_amdgcn_s_waitcnt(0xC07F);  // lgkmcnt(0)
      #pragma unroll
      for (int rt = 0; rt < 2; ++rt) {
        const int row16 = r0 + 32 * wv + 16 * rt;
        const int win = row16 / 144, rg = (row16 - win * 144) >> 4;
        uint2 lo = *(const uint2*)(&bn[wv][rt][l15][4 * g]);
        uint2 hi = *(const uint2*)(&bn[wv][rt][l15][16 + 4 * g]);
        uint4 u; u.x = lo.x; u.y = lo.y; u.z = hi.x; u.w = hi.y;
        ((uint4*)qkvb)[((size_t)((mat * HEADS + h) * NWIN + win)) * 576 + rg * 64 + lane] = u;
      }
      __builtin_amdgcn_s_waitcnt(0xC07F);  // reads done before next hh rewrites bn
    } else {
      // V: D-frag-packed uint2 stores (decoded in attn)
      #pragma unroll
      for (int rt = 0; rt < 2; ++rt) {
        const int row16 = r0 + 32 * wv + 16 * rt;
        const int win = row16 / 144, rg = (row16 - win * 144) >> 4;
        uint2* dst = (uint2*)qkvb + ((size_t)((mat * HEADS + h) * NWIN + win)) * 1152
                     + (rg * 2) * 64 + lane;
        #pragma unroll
        for (int ct = 0; ct < 2; ++ct) dst[ct * 64] = pack4(acc[rt][ct]);
      }
    }
  }
}

// === attention + fused out-proj per (window, head-triple): 9 waves =========
// Per head: S^T=KQ^T+bias(C), exp2, keep-mask, O^T=V^T P^T -> kept in REGS
// (oreg, 2 uint2/head). After head loop, O^T -> ol LDS (aliases dead ks/vt),
// then block finishes ol(72x192) @ w2t + b2 -> out (proj kernel eliminated).
#define VT_LD 164
#define OL_LD 200
__global__ __launch_bounds__(576, 4) void attn7_kernel(
    const uint4* __restrict__ qf, const uint4* __restrict__ kf,
    const uint2* __restrict__ vf, const uint2* __restrict__ biasz,
    const unsigned long long* __restrict__ mq, const uint4* __restrict__ w2t,
    const float* __restrict__ b2, float* __restrict__ out)
{
  __shared__ __align__(16) unsigned char smem[39424];
  uint4 (*ks)[576] = (uint4(*)[576])smem;                          // [2][576] 18432 B
  unsigned short (*vt)[DH][VT_LD] =
      (unsigned short(*)[DH][VT_LD])(smem + 18432);                // [2][32][164] 20992 B
  unsigned short (*ol)[OL_LD] = (unsigned short(*)[OL_LD])smem;    // [80][200] alias (32000 B)
  const int tid = threadIdx.x, wv = tid >> 6, lane = tid & 63;
  const int l15 = lane & 15, g = lane >> 4;
  const int b = blockIdx.x, win = b >> 1, hg = b & 1, h0 = 3 * hg;
  const int wtype = win & (TW - 1);
  const int s = wv;                       // this wave's q-strip
  const int q = 16 * s + l15;
  const int m0 = h0 * NWIN + win;

  // loop-invariant: packed keep-nibbles (9 kst x 4 bits) for this (strip,lane)
  const unsigned long long mw = mq[((size_t)win * 9 + s) * 64 + lane];

  // prologue: stage head h0 into buffer 0; zero V pad cols for both buffers
  {
    ks[0][tid] = kf[(size_t)m0 * 576 + tid];
    const uint2* vs = vf + (size_t)m0 * 1152;
    #pragma unroll
    for (int t = 0; t < 2; ++t) {
      int i = tid + t * 576;
      int fid = i >> 6, ln = i & 63;
      int tok = 16 * (fid >> 1) + 4 * (ln >> 4);
      int d = 16 * (fid & 1) + (ln & 15);
      *(uint2*)(&vt[0][d][tok]) = vs[i];
    }
    #pragma unroll 1
    for (int i = tid; i < 2 * DH * 10; i += 576) {   // cols 144..163 := 0
      int buf = i / 320, rem = i - buf * 320;
      int r = rem / 10, c = 144 + (rem - r * 10) * 2;
      *(unsigned*)(&vt[buf][r][c]) = 0;
    }
  }
  __syncthreads();

  uint2 oreg[3][2];
  #pragma unroll 1
  for (int hh = 0; hh < 3; ++hh) {
    const int cur = hh & 1;
    const int h = h0 + hh;
    const int m = m0 + hh * NWIN;
    // per-head loads, issued up front (consumed after other waves progress)
    uint2 bb[9];
    {
      const uint2* bz = biasz + (((size_t)(wtype * HEADS + h) * 9 + s) * 9) * 64 + lane;
      #pragma unroll
      for (int kst = 0; kst < 9; ++kst) bb[kst] = bz[kst * 64];
    }
    const bf16x8 bq = __builtin_bit_cast(bf16x8, qf[(size_t)m * 576 + s * 64 + lane]);
    // prefetch next head's K/V into registers (LDS write deferred past compute)
    uint4 kreg;
    uint2 vr0, vr1;
    if (hh < 2) {
      kreg = kf[(size_t)(m + NWIN) * 576 + tid];
      const uint2* vs = vf + (size_t)(m + NWIN) * 1152;
      vr0 = vs[tid];
      vr1 = vs[tid + 576];
    }
    // ---- S^T = K Q^T + bias (C-operand); exp2; keep-mask; unnormalized P ----
    float sum = 0.f;
    uint4 pb[5];
    uint2 lo_pk;
    #pragma unroll
    for (int kst = 0; kst < 9; ++kst) {
      f32x4 c;
      c[0] = __uint_as_float(bb[kst].x << 16);
      c[1] = __uint_as_float(bb[kst].x & 0xffff0000u);
      c[2] = __uint_as_float(bb[kst].y << 16);
      c[3] = __uint_as_float(bb[kst].y & 0xffff0000u);
      f32x4 sv = MFMA16(__builtin_bit_cast(bf16x8, ks[cur][kst * 64 + lane]), bq, c);
      const unsigned nib = (unsigned)(mw >> (4 * kst)) & 0xFu;
      #pragma unroll
      for (int j = 0; j < 4; ++j) {
        float p = __builtin_amdgcn_exp2f(sv[j]);
        int keep = ((int)(nib << (31 - j))) >> 31;     // all-ones when keep
        p = __uint_as_float(__float_as_uint(p) & (unsigned)keep);
        sv[j] = p;
        sum += p;
      }
      uint2 pk = pack4(sv);
      if (kst & 1) {
        pb[kst >> 1].x = lo_pk.x; pb[kst >> 1].y = lo_pk.y;
        pb[kst >> 1].z = pk.x;    pb[kst >> 1].w = pk.y;
      } else {
        lo_pk = pk;
      }
    }
    pb[4].x = lo_pk.x; pb[4].y = lo_pk.y; pb[4].z = 0; pb[4].w = 0;
    sum += __shfl_xor(sum, 16);
    sum += __shfl_xor(sum, 32);
    const float inv = 1.f / sum;
    // ---- O^T = V^T P^T, normalize, keep in registers ----
    #pragma unroll
    for (int dt = 0; dt < 2; ++dt) {
      const unsigned short* vrow = &vt[cur][dt * 16 + l15][4 * g];
      f32x4 ot; ot[0] = 0.f; ot[1] = 0.f; ot[2] = 0.f; ot[3] = 0.f;
      #pragma unroll
      for (int s5 = 0; s5 < 5; ++s5)
        ot = MFMA16(ld_frag(vrow + s5 * 32), __builtin_bit_cast(bf16x8, pb[s5]), ot);
      ot[0] *= inv; ot[1] *= inv; ot[2] *= inv; ot[3] *= inv;
      oreg[hh][dt] = pack4(ot);
    }
    // ---- stage next head into the alternate buffer, then one barrier ----
    if (hh < 2) {
      ks[cur ^ 1][tid] = kreg;
      #pragma unroll
      for (int t = 0; t < 2; ++t) {
        int i = tid + t * 576;
        int fid = i >> 6, ln = i & 63;
        int tok = 16 * (fid >> 1) + 4 * (ln >> 4);
        int d = 16 * (fid & 1) + (ln & 15);
        *(uint2*)(&vt[cur ^ 1][d][tok]) = (t == 0) ? vr0 : vr1;
      }
    }
    __syncthreads();   // (hh==2: all ks/vt reads done -> ol alias safe)
  }

  // ---- O^T regs -> ol LDS (scrambled rows: rr = hh*24 + q/6, col (q%6)*32) --
  {
    const int r = q / 6, cb = (q - r * 6) * DH;
    #pragma unroll
    for (int hh = 0; hh < 3; ++hh) {
      *(uint2*)(&ol[hh * 24 + r][cb + 4 * g]) = oreg[hh][0];
      *(uint2*)(&ol[hh * 24 + r][cb + 16 + 4 * g]) = oreg[hh][1];
    }
  }
  __syncthreads();
  // ---- fused out-proj: ol(72x192) @ w2t + b2 -> out rows 24m + r ----------
  // 5 row-tiles (rows 72..79 garbage, guarded) x 12 col-tiles = 60 tiles.
  #pragma unroll 1
  for (int p = wv; p < 60; p += 9) {
    const int rt2 = p / 12, nt = p - rt2 * 12;
    float bv = b2[nt * 16 + l15];
    f32x4 acc; acc[0] = bv; acc[1] = bv; acc[2] = bv; acc[3] = bv;
    const unsigned short* arow = &ol[16 * rt2 + l15][4 * g];
    #pragma unroll
    for (int kk = 0; kk < 6; ++kk)
      acc = MFMA16(ld_frag(arow + kk * 32),
                   __builtin_bit_cast(bf16x8, w2t[(nt * 6 + kk) * 64 + lane]), acc);
    #pragma unroll
    for (int j = 0; j < 4; ++j) {
      int rr = 16 * rt2 + 4 * g + j;
      if (rr < 72) {
        int hh2 = rr / 24, r2 = rr - hh2 * 24;
        size_t grow = (size_t)(24 * ((h0 + hh2) * NWIN + win) + r2);
        out[grow * DIM + nt * 16 + l15] = acc[j];
      }
    }
  }
}

extern "C" void kernel_launch(void* const* d_in, const int* in_sizes, int n_in,
                              void* d_out, int out_size, void* d_ws, size_t ws_size,
                              hipStream_t stream)
{
  const float* x     = (const float*)d_in[0];
  const float* mask  = (const float*)d_in[1];
  const float* w1    = (const float*)d_in[2];
  const float* b1    = (const float*)d_in[3];
  const float* w2    = (const float*)d_in[4];
  const float* b2    = (const float*)d_in[5];
  const float* table = (const float*)d_in[6];
  const int*   pidx  = (const int*)d_in[7];
  float* out = (float*)d_out;
  unsigned char* ws = (unsigned char*)d_ws;
  // ws: w1t 221184 | w2t 73728 | biasz 15925248 | mq 2949120 |
  //     qkvb 106168320 (q-frag | k-frag | v D-frag) |
  //     xb2 35389440 -> 171,048,960 B
  uint4* w1t            = (uint4*)(ws);
  uint4* w2t            = (uint4*)(ws + 221184);
  uint2* biasz          = (uint2*)(ws + 294912);
  unsigned long long* mq = (unsigned long long*)(ws + 16220160);
  unsigned short* qkvb  = (unsigned short*)(ws + 29491200);
  unsigned short* xb2   = (unsigned short*)(ws + 135659520);

  const uint4* qf = (const uint4*)qkvb;
  const uint4* kf = (const uint4*)(ws + 29491200 + 35389440);
  const uint2* vf = (const uint2*)(ws + 29491200 + 70778880);

  megaprep  <<<dim3(2782), dim3(256), 0, stream>>>(x, mask, w1, w2, table, pidx,
                                                   xb2, mq, w1t, w2t, biasz);
  qkv_kernel<<<dim3(4320), dim3(256), 0, stream>>>(xb2, b1, w1t, qkvb);
  attn7_kernel<<<dim3(1280), dim3(576), 0, stream>>>(qf, kf, vf, biasz, mq,
                                                     w2t, b2, out);
}

// Round 18
// 140.382 us; speedup vs baseline: 1.0853x; 1.0853x over previous
//
#include <hip/hip_runtime.h>

#define NWIN 640
#define ZHW  144
#define DIM  192
#define HEADS 6
#define DH   32
#define TW   64
// RSCALE * log2(e): folded into q-projection weights/bias
#define C_FOLD 0.25503450f
#define LOG2E 1.4426950408889634f

typedef float f32x4 __attribute__((ext_vector_type(4)));
typedef __bf16 bf16x8 __attribute__((ext_vector_type(8)));

__device__ __forceinline__ unsigned short f2b(float f) {
  unsigned u = __float_as_uint(f);
  u += 0x7fffu + ((u >> 16) & 1u);
  return (unsigned short)(u >> 16);
}
__device__ __forceinline__ unsigned short cvtb(float f) {
  return __builtin_bit_cast(unsigned short, (__bf16)f);
}
__device__ __forceinline__ uint2 pack4(f32x4 a) {
  uint2 r;
  r.x = (unsigned)cvtb(a[0]) | ((unsigned)cvtb(a[1]) << 16);
  r.y = (unsigned)cvtb(a[2]) | ((unsigned)cvtb(a[3]) << 16);
  return r;
}

// A/B fragment for mfma_f32_16x16x32_bf16 from a row-major array:
// lane reads elements k0..k0+3 and k0+16..k0+19 of its row (k0 = 4*(lane>>4)).
__device__ __forceinline__ bf16x8 ld_frag(const unsigned short* p) {
  uint2 lo = *(const uint2*)(p);
  uint2 hi = *(const uint2*)(p + 16);
  uint4 u; u.x = lo.x; u.y = lo.y; u.z = hi.x; u.w = hi.y;
  return __builtin_bit_cast(bf16x8, u);
}
#define MFMA16(a, b, c) __builtin_amdgcn_mfma_f32_16x16x32_bf16((a), (b), (c), 0, 0, 0)

// ================== megaprep: 4 independent prep jobs, one launch ==========
// LDS 25.1 KB -> 6 blocks/CU; streaming loops fully unrolled (MLP).
// [0,1440)    conv_x  : x f32 -> xb2 bf16 A-frag-packed (64-row tiles)
// [1440,2088) bias    : table gather -> biasz frag-packed (48-wh chunks)
// [2088,2728) mask    : mask f32 -> per-(win,strip,lane) u64 keep-nibbles
// [2728,2782) weights : w1/w2 -> B-frag-packed bf16
#define MP_BIAS0 1440
#define MP_MASK0 2088
#define MP_W0    2728
__global__ __launch_bounds__(256) void megaprep(
    const float* __restrict__ x, const float* __restrict__ mask,
    const float* __restrict__ w1, const float* __restrict__ w2,
    const float* __restrict__ table, const int* __restrict__ pidx,
    unsigned short* __restrict__ xb2, unsigned long long* __restrict__ mq,
    uint4* __restrict__ w1t, uint4* __restrict__ w2t,
    uint2* __restrict__ biasz)
{
  __shared__ __align__(16) unsigned char smem[25088];
  const int tid = threadIdx.x;
  const int b = blockIdx.x;

  if (b < MP_BIAS0) {
    // ---------------- conv_x (64-row tile) ----------------
    unsigned short (*xl)[196] = (unsigned short(*)[196])smem;  // [64][196]
    const int r0 = b * 64;
    const float4* src = (const float4*)(x + (size_t)r0 * DIM);
    float4 v[12];
    #pragma unroll
    for (int u = 0; u < 12; ++u) v[u] = src[tid + 256 * u];
    #pragma unroll
    for (int u = 0; u < 12; ++u) {
      int i = tid + 256 * u;
      int e = i * 4, r = e / DIM, c = e % DIM;
      uint2 pk;
      pk.x = (unsigned)f2b(v[u].x) | ((unsigned)f2b(v[u].y) << 16);
      pk.y = (unsigned)f2b(v[u].z) | ((unsigned)f2b(v[u].w) << 16);
      *(uint2*)(&xl[r][c]) = pk;
    }
    __syncthreads();
    uint4* dst = (uint4*)xb2 + (size_t)b * 1536;
    #pragma unroll
    for (int u = 0; u < 6; ++u) {
      int o = tid + 256 * u;
      int rt = o / 384, rem = o - rt * 384, kk = rem >> 6, ln = rem & 63;
      const unsigned short* p = &xl[16 * rt + (ln & 15)][32 * kk + 4 * (ln >> 4)];
      uint2 lo = *(const uint2*)p;
      uint2 hi = *(const uint2*)(p + 16);
      uint4 u4; u4.x = lo.x; u4.y = lo.y; u4.z = hi.x; u4.w = hi.y;
      dst[o] = u4;
    }
  } else if (b < MP_MASK0) {
    // ---------------- bias direct to biasz (48-wh chunk) ----------------
    unsigned short (*tile)[49] = (unsigned short(*)[49])smem;  // [256][49]
    const int b2 = b - MP_BIAS0;
    const int whc = b2 & 7, rem2 = b2 >> 3;       // 648 = 81 * 8
    const int s = rem2 / 9, kst = rem2 - 9 * (rem2 / 9);
    int rowi[12];
    #pragma unroll
    for (int u = 0; u < 12; ++u) {
      int idx = tid + 256 * u;
      int pos = idx / 12;
      int q = 16 * s + (pos >> 4), kk = 16 * kst + (pos & 15);
      rowi[u] = pidx[q * ZHW + kk];
    }
    float4 v[12];
    #pragma unroll
    for (int u = 0; u < 12; ++u) {
      int idx = tid + 256 * u;
      int pos = idx / 12, t = idx - pos * 12;
      v[u] = *(const float4*)(table + (size_t)rowi[u] * 384 + whc * 48 + t * 4);
    }
    #pragma unroll
    for (int u = 0; u < 12; ++u) {
      int idx = tid + 256 * u;
      int pos = idx / 12, t = idx - pos * 12;
      tile[pos][t * 4 + 0] = f2b(v[u].x * LOG2E);
      tile[pos][t * 4 + 1] = f2b(v[u].y * LOG2E);
      tile[pos][t * 4 + 2] = f2b(v[u].z * LOG2E);
      tile[pos][t * 4 + 3] = f2b(v[u].w * LOG2E);
    }
    __syncthreads();
    #pragma unroll
    for (int u = 0; u < 12; ++u) {
      int o = tid + 256 * u;
      int wh = o >> 6, lane = o & 63;
      int lp = (lane & 15) * 16 + 4 * (lane >> 4);
      uint2 uu;
      uu.x = (unsigned)tile[lp + 0][wh] | ((unsigned)tile[lp + 1][wh] << 16);
      uu.y = (unsigned)tile[lp + 2][wh] | ((unsigned)tile[lp + 3][wh] << 16);
      biasz[(((size_t)(whc * 48 + wh) * 9 + s) * 9 + kst) * 64 + lane] = uu;
    }
  } else if (b < MP_W0) {
    // ---------------- mask -> keep-nibble u64 ----------------
    unsigned char* ms = (unsigned char*)smem;  // [2592]
    const int win = b - MP_MASK0;
    const float4* src = (const float4*)(mask + (size_t)win * (ZHW * ZHW));
    float4 a[10], c[10];
    #pragma unroll
    for (int u = 0; u < 10; ++u) {
      int i = tid + 256 * u;
      a[u] = src[2 * i];
      c[u] = src[2 * i + 1];
    }
    float4 at, ct;
    if (tid < 32) { at = src[2 * (2560 + tid)]; ct = src[2 * (2560 + tid) + 1]; }
    #pragma unroll
    for (int u = 0; u < 10; ++u) {
      int i = tid + 256 * u;
      unsigned v = (a[u].x == 0.f ? 1u : 0u) | (a[u].y == 0.f ? 2u : 0u) |
                   (a[u].z == 0.f ? 4u : 0u) | (a[u].w == 0.f ? 8u : 0u) |
                   (c[u].x == 0.f ? 16u : 0u) | (c[u].y == 0.f ? 32u : 0u) |
                   (c[u].z == 0.f ? 64u : 0u) | (c[u].w == 0.f ? 128u : 0u);
      ms[i] = (unsigned char)v;
    }
    if (tid < 32) {
      unsigned v = (at.x == 0.f ? 1u : 0u) | (at.y == 0.f ? 2u : 0u) |
                   (at.z == 0.f ? 4u : 0u) | (at.w == 0.f ? 8u : 0u) |
                   (ct.x == 0.f ? 16u : 0u) | (ct.y == 0.f ? 32u : 0u) |
                   (ct.z == 0.f ? 64u : 0u) | (ct.w == 0.f ? 128u : 0u);
      ms[2560 + tid] = (unsigned char)v;
    }
    __syncthreads();
    #pragma unroll
    for (int u = 0; u < 3; ++u) {
      int o = tid + 256 * u;
      if (o < 576) {
        int s = o >> 6, ln = o & 63;
        int qq = 16 * s + (ln & 15), g = ln >> 4;
        int base = qq * 18 + (g >> 1);
        int nsh = 4 * (g & 1);
        unsigned long long mw = 0;
        #pragma unroll
        for (int kst = 0; kst < 9; ++kst) {
          unsigned nib = ((unsigned)ms[base + 2 * kst] >> nsh) & 0xFu;
          mw |= (unsigned long long)nib << (4 * kst);
        }
        mq[(size_t)win * 576 + o] = mw;
      }
    }
  } else {
    // ---------------- weights -> B-frag-packed ----------------
    int t = (b - MP_W0) * 256 + tid;
    if (t < 13824) {
      int lane = t & 63, r = t >> 6;
      int kk = r % 6, ntg = r / 6;
      int n = ntg * 16 + (lane & 15);
      int k0 = kk * 32 + 4 * ((lane >> 4) & 3);
      float sc = (n < 192) ? C_FOLD : 1.0f;
      unsigned short e[8];
      #pragma unroll
      for (int j = 0; j < 4; ++j) e[j]     = f2b(w1[(size_t)(k0 + j) * 576 + n] * sc);
      #pragma unroll
      for (int j = 0; j < 4; ++j) e[4 + j] = f2b(w1[(size_t)(k0 + 16 + j) * 576 + n] * sc);
      uint4 u;
      u.x = (unsigned)e[0] | ((unsigned)e[1] << 16);
      u.y = (unsigned)e[2] | ((unsigned)e[3] << 16);
      u.z = (unsigned)e[4] | ((unsigned)e[5] << 16);
      u.w = (unsigned)e[6] | ((unsigned)e[7] << 16);
      w1t[t] = u;
    }
    if (t < 4608) {
      int lane = t & 63, r = t >> 6;
      int kk = r % 6, ntg = r / 6;
      int n = ntg * 16 + (lane & 15);
      int k0 = kk * 32 + 4 * ((lane >> 4) & 3);
      unsigned short e[8];
      #pragma unroll
      for (int j = 0; j < 4; ++j) e[j]     = f2b(w2[(size_t)(k0 + j) * 192 + n]);
      #pragma unroll
      for (int j = 0; j < 4; ++j) e[4 + j] = f2b(w2[(size_t)(k0 + 16 + j) * 192 + n]);
      uint4 u;
      u.x = (unsigned)e[0] | ((unsigned)e[1] << 16);
      u.y = (unsigned)e[2] | ((unsigned)e[3] << 16);
      u.z = (unsigned)e[4] | ((unsigned)e[5] << 16);
      u.w = (unsigned)e[6] | ((unsigned)e[7] << 16);
      w2t[t] = u;
    }
  }
}

// ===================== QKV projection (tiled GEMM) =========================
// xb2 A-frag-packed; w1t B-frag-packed (uint4/lane); XCD-swizzled grid.
// Outputs: q,k MFMA-frag-packed uint4; v D-frag uint2.
__global__ __launch_bounds__(256) void qkv_kernel(
    const unsigned short* __restrict__ xb2, const float* __restrict__ b1,
    const uint4* __restrict__ w1t, unsigned short* __restrict__ qkvb)
{
  __shared__ __align__(16) uint4 wb4[2304];                 // 36864 B
  __shared__ __align__(16) unsigned short bn[4][2][16][38]; //  9728 B
  const int tid = threadIdx.x, wv = tid >> 6, lane = tid & 63;
  const int l15 = lane & 15, g = lane >> 4;
  // XCD swizzle: each XCD gets 90 contiguous mt's; the 6 same-mt blocks
  // land on one XCD (A-tile L2 reuse). 4320 = 8 XCD * 540.
  const int b = blockIdx.x;
  const int lid = (b & 7) * 540 + (b >> 3);
  const int mt = lid / 6, ch = lid - mt * 6;
  const int r0 = mt * 128;

  {
    const uint4* wsrc = w1t + (size_t)ch * 2304;
    #pragma unroll 1
    for (int i = tid; i < 2304; i += 256) wb4[i] = wsrc[i];
  }
  bf16x8 xa[2][6];
  {
    const uint4* asrc = (const uint4*)xb2;
    const int rt0 = mt * 8 + 2 * wv;
    #pragma unroll
    for (int rt = 0; rt < 2; ++rt)
      #pragma unroll
      for (int kk = 0; kk < 6; ++kk)
        xa[rt][kk] = __builtin_bit_cast(bf16x8,
            asrc[((size_t)(rt0 + rt) * 6 + kk) * 64 + lane]);
  }
  __syncthreads();
  const int mat = ch >> 1;
  const float bscale = (mat == 0) ? C_FOLD : 1.0f;
  #pragma unroll 1
  for (int hh = 0; hh < 3; ++hh) {
    const int h = (ch & 1) * 3 + hh;
    f32x4 acc[2][2];
    {
      float bv0 = b1[ch * 96 + hh * 32 + l15] * bscale;
      float bv1 = b1[ch * 96 + hh * 32 + 16 + l15] * bscale;
      #pragma unroll
      for (int rt = 0; rt < 2; ++rt) {
        acc[rt][0][0] = bv0; acc[rt][0][1] = bv0; acc[rt][0][2] = bv0; acc[rt][0][3] = bv0;
        acc[rt][1][0] = bv1; acc[rt][1][1] = bv1; acc[rt][1][2] = bv1; acc[rt][1][3] = bv1;
      }
    }
    #pragma unroll
    for (int kk = 0; kk < 6; ++kk) {
      bf16x8 b0  = __builtin_bit_cast(bf16x8, wb4[((2 * hh)     * 6 + kk) * 64 + lane]);
      bf16x8 b1f = __builtin_bit_cast(bf16x8, wb4[((2 * hh + 1) * 6 + kk) * 64 + lane]);
      acc[0][0] = MFMA16(xa[0][kk], b0, acc[0][0]);
      acc[0][1] = MFMA16(xa[0][kk], b1f, acc[0][1]);
      acc[1][0] = MFMA16(xa[1][kk], b0, acc[1][0]);
      acc[1][1] = MFMA16(xa[1][kk], b1f, acc[1][1]);
    }
    if (mat < 2) {
      // bounce to LDS (D layout) then read back as frags -> coalesced uint4
      #pragma unroll
      for (int rt = 0; rt < 2; ++rt)
        #pragma unroll
        for (int ct = 0; ct < 2; ++ct)
          #pragma unroll
          for (int j = 0; j < 4; ++j)
            bn[wv][rt][4 * g + j][16 * ct + l15] = cvtb(acc[rt][ct][j]);
      __builtin_amdgcn_s_waitcnt(0xC07F);  // lgkmcnt(0)
      #pragma unroll
      for (int rt = 0; rt < 2; ++rt) {
        const int row16 = r0 + 32 * wv + 16 * rt;
        const int win = row16 / 144, rg = (row16 - win * 144) >> 4;
        uint2 lo = *(const uint2*)(&bn[wv][rt][l15][4 * g]);
        uint2 hi = *(const uint2*)(&bn[wv][rt][l15][16 + 4 * g]);
        uint4 u; u.x = lo.x; u.y = lo.y; u.z = hi.x; u.w = hi.y;
        ((uint4*)qkvb)[((size_t)((mat * HEADS + h) * NWIN + win)) * 576 + rg * 64 + lane] = u;
      }
      __builtin_amdgcn_s_waitcnt(0xC07F);  // reads done before next hh rewrites bn
    } else {
      // V: D-frag-packed uint2 stores (decoded in attn)
      #pragma unroll
      for (int rt = 0; rt < 2; ++rt) {
        const int row16 = r0 + 32 * wv + 16 * rt;
        const int win = row16 / 144, rg = (row16 - win * 144) >> 4;
        uint2* dst = (uint2*)qkvb + ((size_t)((mat * HEADS + h) * NWIN + win)) * 1152
                     + (rg * 2) * 64 + lane;
        #pragma unroll
        for (int ct = 0; ct < 2; ++ct) dst[ct * 64] = pack4(acc[rt][ct]);
      }
    }
  }
}

// === attention per (window, head-triple): 9 waves, 3 heads, dbuf K/V ======
#define VT_LD 164
__global__ __launch_bounds__(576, 4) void attn6_kernel(
    const uint4* __restrict__ qf, const uint4* __restrict__ kf,
    const uint2* __restrict__ vf, const uint2* __restrict__ biasz,
    const unsigned long long* __restrict__ mq, unsigned short* __restrict__ xbuf)
{
  __shared__ __align__(16) uint4 ks[2][576];               // 18432 B
  __shared__ __align__(16) unsigned short vt[2][DH][VT_LD];// 20992 B
  const int tid = threadIdx.x, wv = tid >> 6, lane = tid & 63;
  const int l15 = lane & 15, g = lane >> 4;
  const int b = blockIdx.x, win = b >> 1, hg = b & 1, h0 = 3 * hg;
  const int wtype = win & (TW - 1);
  const int s = wv;                       // this wave's q-strip
  const int q = 16 * s + l15;
  const int m0 = h0 * NWIN + win;

  // loop-invariant: packed keep-nibbles (9 kst x 4 bits) for this (strip,lane)
  const unsigned long long mw = mq[((size_t)win * 9 + s) * 64 + lane];

  // prologue: stage head h0 into buffer 0; zero V pad cols for both buffers
  {
    ks[0][tid] = kf[(size_t)m0 * 576 + tid];
    const uint2* vs = vf + (size_t)m0 * 1152;
    #pragma unroll
    for (int t = 0; t < 2; ++t) {
      int i = tid + t * 576;
      int fid = i >> 6, ln = i & 63;
      int tok = 16 * (fid >> 1) + 4 * (ln >> 4);
      int d = 16 * (fid & 1) + (ln & 15);
      *(uint2*)(&vt[0][d][tok]) = vs[i];
    }
    #pragma unroll 1
    for (int i = tid; i < 2 * DH * 10; i += 576) {   // cols 144..163 := 0
      int buf = i / 320, rem = i - buf * 320;
      int r = rem / 10, c = 144 + (rem - r * 10) * 2;
      *(unsigned*)(&vt[buf][r][c]) = 0;
    }
  }
  __syncthreads();

  #pragma unroll 1
  for (int hh = 0; hh < 3; ++hh) {
    const int cur = hh & 1;
    const int h = h0 + hh;
    const int m = m0 + hh * NWIN;
    // per-head loads, issued up front (consumed after other waves progress)
    uint2 bb[9];
    {
      const uint2* bz = biasz + (((size_t)(wtype * HEADS + h) * 9 + s) * 9) * 64 + lane;
      #pragma unroll
      for (int kst = 0; kst < 9; ++kst) bb[kst] = bz[kst * 64];
    }
    const bf16x8 bq = __builtin_bit_cast(bf16x8, qf[(size_t)m * 576 + s * 64 + lane]);
    // prefetch next head's K/V into registers (LDS write deferred past compute)
    uint4 kreg;
    uint2 vr0, vr1;
    if (hh < 2) {
      kreg = kf[(size_t)(m + NWIN) * 576 + tid];
      const uint2* vs = vf + (size_t)(m + NWIN) * 1152;
      vr0 = vs[tid];
      vr1 = vs[tid + 576];
    }
    // ---- S^T = K Q^T + bias (C-operand); exp2; keep-mask; unnormalized P ----
    float sum = 0.f;
    uint4 pb[5];
    uint2 lo_pk;
    #pragma unroll
    for (int kst = 0; kst < 9; ++kst) {
      f32x4 c;
      c[0] = __uint_as_float(bb[kst].x << 16);
      c[1] = __uint_as_float(bb[kst].x & 0xffff0000u);
      c[2] = __uint_as_float(bb[kst].y << 16);
      c[3] = __uint_as_float(bb[kst].y & 0xffff0000u);
      f32x4 sv = MFMA16(__builtin_bit_cast(bf16x8, ks[cur][kst * 64 + lane]), bq, c);
      const unsigned nib = (unsigned)(mw >> (4 * kst)) & 0xFu;
      #pragma unroll
      for (int j = 0; j < 4; ++j) {
        float p = __builtin_amdgcn_exp2f(sv[j]);
        int keep = ((int)(nib << (31 - j))) >> 31;     // all-ones when keep
        p = __uint_as_float(__float_as_uint(p) & (unsigned)keep);
        sv[j] = p;
        sum += p;
      }
      uint2 pk = pack4(sv);
      if (kst & 1) {
        pb[kst >> 1].x = lo_pk.x; pb[kst >> 1].y = lo_pk.y;
        pb[kst >> 1].z = pk.x;    pb[kst >> 1].w = pk.y;
      } else {
        lo_pk = pk;
      }
    }
    pb[4].x = lo_pk.x; pb[4].y = lo_pk.y; pb[4].z = 0; pb[4].w = 0;
    sum += __shfl_xor(sum, 16);
    sum += __shfl_xor(sum, 32);
    const float inv = 1.f / sum;
    // ---- O^T = V^T P^T, normalize at store; scrambled xbuf layout ----
    const int r = q / 6, cb = (q - r * 6) * DH;
    unsigned short* xrow = xbuf + (size_t)(24 * m + r) * DIM + cb + 4 * g;
    #pragma unroll
    for (int dt = 0; dt < 2; ++dt) {
      const unsigned short* vrow = &vt[cur][dt * 16 + l15][4 * g];
      f32x4 ot; ot[0] = 0.f; ot[1] = 0.f; ot[2] = 0.f; ot[3] = 0.f;
      #pragma unroll
      for (int s5 = 0; s5 < 5; ++s5)
        ot = MFMA16(ld_frag(vrow + s5 * 32), __builtin_bit_cast(bf16x8, pb[s5]), ot);
      ot[0] *= inv; ot[1] *= inv; ot[2] *= inv; ot[3] *= inv;
      *(uint2*)(xrow + dt * 16) = pack4(ot);
    }
    // ---- stage next head into the alternate buffer, then one barrier ----
    if (hh < 2) {
      ks[cur ^ 1][tid] = kreg;
      #pragma unroll
      for (int t = 0; t < 2; ++t) {
        int i = tid + t * 576;
        int fid = i >> 6, ln = i & 63;
        int tok = 16 * (fid >> 1) + 4 * (ln >> 4);
        int d = 16 * (fid & 1) + (ln & 15);
        *(uint2*)(&vt[cur ^ 1][d][tok]) = (t == 0) ? vr0 : vr1;
      }
    }
    __syncthreads();
  }
}

// ============ out projection: xbuf(92160x192 bf16) @ w2 + b2 ==============
// Two 96-col chunks (36.9 KB LDS -> 4 blocks/CU).
__global__ __launch_bounds__(512) void proj_kernel(
    const unsigned short* __restrict__ xbuf, const uint4* __restrict__ w2t,
    const float* __restrict__ b2, float* __restrict__ out)
{
  __shared__ __align__(16) uint4 wb4[2304];  // 36864 B (one 96-col chunk)
  const int tid = threadIdx.x, wv = tid >> 6, lane = tid & 63;
  const int l15 = lane & 15, g = lane >> 4;
  const int r0 = blockIdx.x * 128;
  bf16x8 xa[6];
  {
    const unsigned short* xrow = xbuf + (size_t)(r0 + 16 * wv + l15) * DIM;
    #pragma unroll
    for (int kk = 0; kk < 6; ++kk) xa[kk] = ld_frag(xrow + kk * 32 + 4 * g);
  }
  #pragma unroll 1
  for (int ch = 0; ch < 2; ++ch) {
    __syncthreads();
    {
      const uint4* wsrc = w2t + (size_t)ch * 2304;
      #pragma unroll 1
      for (int i = tid; i < 2304; i += 512) wb4[i] = wsrc[i];
    }
    __syncthreads();
    #pragma unroll 1
    for (int nt = 0; nt < 6; ++nt) {
      const int n = ch * 96 + nt * 16 + l15;
      float bv = b2[n];
      f32x4 acc; acc[0] = bv; acc[1] = bv; acc[2] = bv; acc[3] = bv;
      #pragma unroll
      for (int kk = 0; kk < 6; ++kk)
        acc = MFMA16(xa[kk], __builtin_bit_cast(bf16x8, wb4[(nt * 6 + kk) * 64 + lane]), acc);
      #pragma unroll
      for (int j = 0; j < 4; ++j)
        out[(size_t)(r0 + 16 * wv + 4 * g + j) * DIM + n] = acc[j];
    }
  }
}

extern "C" void kernel_launch(void* const* d_in, const int* in_sizes, int n_in,
                              void* d_out, int out_size, void* d_ws, size_t ws_size,
                              hipStream_t stream)
{
  const float* x     = (const float*)d_in[0];
  const float* mask  = (const float*)d_in[1];
  const float* w1    = (const float*)d_in[2];
  const float* b1    = (const float*)d_in[3];
  const float* w2    = (const float*)d_in[4];
  const float* b2    = (const float*)d_in[5];
  const float* table = (const float*)d_in[6];
  const int*   pidx  = (const int*)d_in[7];
  float* out = (float*)d_out;
  unsigned char* ws = (unsigned char*)d_ws;
  // ws: w1t 221184 | w2t 73728 | biasz 15925248 | mq 2949120 |
  //     qkvb 106168320 (q-frag | k-frag | v D-frag) |
  //     xbuf 35389440 (xb2 aliases; dead before attn6 writes) -> 171,048,960 B
  uint4* w1t            = (uint4*)(ws);
  uint4* w2t            = (uint4*)(ws + 221184);
  uint2* biasz          = (uint2*)(ws + 294912);
  unsigned long long* mq = (unsigned long long*)(ws + 16220160);
  unsigned short* qkvb  = (unsigned short*)(ws + 29491200);
  unsigned short* xbuf  = (unsigned short*)(ws + 135659520);
  unsigned short* xb2   = xbuf;   // alias: consumed by qkv before attn6 writes

  const uint4* qf = (const uint4*)qkvb;
  const uint4* kf = (const uint4*)(ws + 29491200 + 35389440);
  const uint2* vf = (const uint2*)(ws + 29491200 + 70778880);

  megaprep  <<<dim3(2782), dim3(256), 0, stream>>>(x, mask, w1, w2, table, pidx,
                                                   xb2, mq, w1t, w2t, biasz);
  qkv_kernel<<<dim3(4320), dim3(256), 0, stream>>>(xb2, b1, w1t, qkvb);
  attn6_kernel<<<dim3(1280), dim3(576), 0, stream>>>(qf, kf, vf, biasz, mq, xbuf);
  proj_kernel<<<dim3(720), dim3(512), 0, stream>>>(xbuf, w2t, b2, out);
}

// Round 19
// 138.931 us; speedup vs baseline: 1.0966x; 1.0104x over previous
//
#include <hip/hip_runtime.h>

#define NWIN 640
#define ZHW  144
#define DIM  192
#define HEADS 6
#define DH   32
#define TW   64
// RSCALE * log2(e): folded into q-projection weights/bias
#define C_FOLD 0.25503450f
#define LOG2E 1.4426950408889634f

typedef float f32x4 __attribute__((ext_vector_type(4)));
typedef __bf16 bf16x8 __attribute__((ext_vector_type(8)));

__device__ __forceinline__ unsigned short f2b(float f) {
  unsigned u = __float_as_uint(f);
  u += 0x7fffu + ((u >> 16) & 1u);
  return (unsigned short)(u >> 16);
}
__device__ __forceinline__ unsigned short cvtb(float f) {
  return __builtin_bit_cast(unsigned short, (__bf16)f);
}
__device__ __forceinline__ uint2 pack4(f32x4 a) {
  uint2 r;
  r.x = (unsigned)cvtb(a[0]) | ((unsigned)cvtb(a[1]) << 16);
  r.y = (unsigned)cvtb(a[2]) | ((unsigned)cvtb(a[3]) << 16);
  return r;
}

// A/B fragment for mfma_f32_16x16x32_bf16 from a row-major array:
// lane reads elements k0..k0+3 and k0+16..k0+19 of its row (k0 = 4*(lane>>4)).
__device__ __forceinline__ bf16x8 ld_frag(const unsigned short* p) {
  uint2 lo = *(const uint2*)(p);
  uint2 hi = *(const uint2*)(p + 16);
  uint4 u; u.x = lo.x; u.y = lo.y; u.z = hi.x; u.w = hi.y;
  return __builtin_bit_cast(bf16x8, u);
}
#define MFMA16(a, b, c) __builtin_amdgcn_mfma_f32_16x16x32_bf16((a), (b), (c), 0, 0, 0)

// async global->LDS, 4 B/lane: lane i's data (from its own gaddr) lands at
// lds_base + 4*i. No VGPR round-trip -> deep MLP (fire-and-forget).
__device__ __forceinline__ void gld_lds4(const float* g, float* l) {
  __builtin_amdgcn_global_load_lds(
      (const __attribute__((address_space(1))) unsigned int*)g,
      (__attribute__((address_space(3))) unsigned int*)l, 4, 0, 0);
}

// ================== megaprep: 4 independent prep jobs, one launch ==========
// LDS 25.1 KB -> 6 blocks/CU.
// [0,2880)    conv_x  : x f32 -> async-LDS (f32, padded) -> xb2 bf16 A-frags
// [2880,3528) bias    : table gather -> biasz frag-packed (48-wh chunks)
// [3528,4168) mask    : mask f32 -> per-(win,strip,lane) u64 keep-nibbles
// [4168,4222) weights : w1/w2 -> B-frag-packed bf16
#define MP_BIAS0 2880
#define MP_MASK0 3528
#define MP_W0    4168
__global__ __launch_bounds__(256) void megaprep(
    const float* __restrict__ x, const float* __restrict__ mask,
    const float* __restrict__ w1, const float* __restrict__ w2,
    const float* __restrict__ table, const int* __restrict__ pidx,
    unsigned short* __restrict__ xb2, unsigned long long* __restrict__ mq,
    uint4* __restrict__ w1t, uint4* __restrict__ w2t,
    uint2* __restrict__ biasz)
{
  __shared__ __align__(16) unsigned char smem[25088];
  const int tid = threadIdx.x;
  const int b = blockIdx.x;

  if (b < MP_BIAS0) {
    // ------- conv_x (32-row tile, async f32 staging, read-side convert) ----
    float (*xl)[196] = (float(*)[196])smem;   // [32][196] f32 = 25088 B
    const int r0 = b * 32;
    const float* src = x + (size_t)r0 * DIM;
    const int wv = tid >> 6, lane = tid & 63;
    // wave wv stages rows [8wv, 8wv+8): 3 x 64-float segments per row,
    // 24 outstanding global_load_lds per wave (no VGPR round-trip).
    #pragma unroll
    for (int rr = 0; rr < 8; ++rr) {
      const int row = 8 * wv + rr;
      const float* g = src + row * DIM + lane;
      float* l = &xl[row][0];
      gld_lds4(g, l);
      gld_lds4(g + 64, l + 64);
      gld_lds4(g + 128, l + 128);
    }
    __syncthreads();   // drains vmcnt (async LDS writes) + barrier
    uint4* dst = (uint4*)xb2 + (size_t)b * 768;
    #pragma unroll
    for (int u = 0; u < 3; ++u) {   // 2 rt * 6 kk * 64 = 768 outputs
      int o = tid + 256 * u;
      int rt = o / 384, rem = o - rt * 384, kk = rem >> 6, ln = rem & 63;
      const float* p = &xl[16 * rt + (ln & 15)][32 * kk + 4 * (ln >> 4)];
      uint4 u4;
      u4.x = (unsigned)f2b(p[0])  | ((unsigned)f2b(p[1])  << 16);
      u4.y = (unsigned)f2b(p[2])  | ((unsigned)f2b(p[3])  << 16);
      u4.z = (unsigned)f2b(p[16]) | ((unsigned)f2b(p[17]) << 16);
      u4.w = (unsigned)f2b(p[18]) | ((unsigned)f2b(p[19]) << 16);
      dst[o] = u4;
    }
  } else if (b < MP_MASK0) {
    // ---------------- bias direct to biasz (48-wh chunk) ----------------
    unsigned short (*tile)[49] = (unsigned short(*)[49])smem;  // [256][49]
    const int b2 = b - MP_BIAS0;
    const int whc = b2 & 7, rem2 = b2 >> 3;       // 648 = 81 * 8
    const int s = rem2 / 9, kst = rem2 - 9 * (rem2 / 9);
    int rowi[12];
    #pragma unroll
    for (int u = 0; u < 12; ++u) {
      int idx = tid + 256 * u;
      int pos = idx / 12;
      int q = 16 * s + (pos >> 4), kk = 16 * kst + (pos & 15);
      rowi[u] = pidx[q * ZHW + kk];
    }
    float4 v[12];
    #pragma unroll
    for (int u = 0; u < 12; ++u) {
      int idx = tid + 256 * u;
      int pos = idx / 12, t = idx - pos * 12;
      v[u] = *(const float4*)(table + (size_t)rowi[u] * 384 + whc * 48 + t * 4);
    }
    #pragma unroll
    for (int u = 0; u < 12; ++u) {
      int idx = tid + 256 * u;
      int pos = idx / 12, t = idx - pos * 12;
      tile[pos][t * 4 + 0] = f2b(v[u].x * LOG2E);
      tile[pos][t * 4 + 1] = f2b(v[u].y * LOG2E);
      tile[pos][t * 4 + 2] = f2b(v[u].z * LOG2E);
      tile[pos][t * 4 + 3] = f2b(v[u].w * LOG2E);
    }
    __syncthreads();
    #pragma unroll
    for (int u = 0; u < 12; ++u) {
      int o = tid + 256 * u;
      int wh = o >> 6, lane = o & 63;
      int lp = (lane & 15) * 16 + 4 * (lane >> 4);
      uint2 uu;
      uu.x = (unsigned)tile[lp + 0][wh] | ((unsigned)tile[lp + 1][wh] << 16);
      uu.y = (unsigned)tile[lp + 2][wh] | ((unsigned)tile[lp + 3][wh] << 16);
      biasz[(((size_t)(whc * 48 + wh) * 9 + s) * 9 + kst) * 64 + lane] = uu;
    }
  } else if (b < MP_W0) {
    // ---------------- mask -> keep-nibble u64 ----------------
    unsigned char* ms = (unsigned char*)smem;  // [2592]
    const int win = b - MP_MASK0;
    const float4* src = (const float4*)(mask + (size_t)win * (ZHW * ZHW));
    float4 a[10], c[10];
    #pragma unroll
    for (int u = 0; u < 10; ++u) {
      int i = tid + 256 * u;
      a[u] = src[2 * i];
      c[u] = src[2 * i + 1];
    }
    float4 at, ct;
    if (tid < 32) { at = src[2 * (2560 + tid)]; ct = src[2 * (2560 + tid) + 1]; }
    #pragma unroll
    for (int u = 0; u < 10; ++u) {
      int i = tid + 256 * u;
      unsigned v = (a[u].x == 0.f ? 1u : 0u) | (a[u].y == 0.f ? 2u : 0u) |
                   (a[u].z == 0.f ? 4u : 0u) | (a[u].w == 0.f ? 8u : 0u) |
                   (c[u].x == 0.f ? 16u : 0u) | (c[u].y == 0.f ? 32u : 0u) |
                   (c[u].z == 0.f ? 64u : 0u) | (c[u].w == 0.f ? 128u : 0u);
      ms[i] = (unsigned char)v;
    }
    if (tid < 32) {
      unsigned v = (at.x == 0.f ? 1u : 0u) | (at.y == 0.f ? 2u : 0u) |
                   (at.z == 0.f ? 4u : 0u) | (at.w == 0.f ? 8u : 0u) |
                   (ct.x == 0.f ? 16u : 0u) | (ct.y == 0.f ? 32u : 0u) |
                   (ct.z == 0.f ? 64u : 0u) | (ct.w == 0.f ? 128u : 0u);
      ms[2560 + tid] = (unsigned char)v;
    }
    __syncthreads();
    #pragma unroll
    for (int u = 0; u < 3; ++u) {
      int o = tid + 256 * u;
      if (o < 576) {
        int s = o >> 6, ln = o & 63;
        int qq = 16 * s + (ln & 15), g = ln >> 4;
        int base = qq * 18 + (g >> 1);
        int nsh = 4 * (g & 1);
        unsigned long long mw = 0;
        #pragma unroll
        for (int kst = 0; kst < 9; ++kst) {
          unsigned nib = ((unsigned)ms[base + 2 * kst] >> nsh) & 0xFu;
          mw |= (unsigned long long)nib << (4 * kst);
        }
        mq[(size_t)win * 576 + o] = mw;
      }
    }
  } else {
    // ---------------- weights -> B-frag-packed ----------------
    int t = (b - MP_W0) * 256 + tid;
    if (t < 13824) {
      int lane = t & 63, r = t >> 6;
      int kk = r % 6, ntg = r / 6;
      int n = ntg * 16 + (lane & 15);
      int k0 = kk * 32 + 4 * ((lane >> 4) & 3);
      float sc = (n < 192) ? C_FOLD : 1.0f;
      unsigned short e[8];
      #pragma unroll
      for (int j = 0; j < 4; ++j) e[j]     = f2b(w1[(size_t)(k0 + j) * 576 + n] * sc);
      #pragma unroll
      for (int j = 0; j < 4; ++j) e[4 + j] = f2b(w1[(size_t)(k0 + 16 + j) * 576 + n] * sc);
      uint4 u;
      u.x = (unsigned)e[0] | ((unsigned)e[1] << 16);
      u.y = (unsigned)e[2] | ((unsigned)e[3] << 16);
      u.z = (unsigned)e[4] | ((unsigned)e[5] << 16);
      u.w = (unsigned)e[6] | ((unsigned)e[7] << 16);
      w1t[t] = u;
    }
    if (t < 4608) {
      int lane = t & 63, r = t >> 6;
      int kk = r % 6, ntg = r / 6;
      int n = ntg * 16 + (lane & 15);
      int k0 = kk * 32 + 4 * ((lane >> 4) & 3);
      unsigned short e[8];
      #pragma unroll
      for (int j = 0; j < 4; ++j) e[j]     = f2b(w2[(size_t)(k0 + j) * 192 + n]);
      #pragma unroll
      for (int j = 0; j < 4; ++j) e[4 + j] = f2b(w2[(size_t)(k0 + 16 + j) * 192 + n]);
      uint4 u;
      u.x = (unsigned)e[0] | ((unsigned)e[1] << 16);
      u.y = (unsigned)e[2] | ((unsigned)e[3] << 16);
      u.z = (unsigned)e[4] | ((unsigned)e[5] << 16);
      u.w = (unsigned)e[6] | ((unsigned)e[7] << 16);
      w2t[t] = u;
    }
  }
}

// ===================== QKV projection (tiled GEMM) =========================
// xb2 A-frag-packed; w1t B-frag-packed (uint4/lane); XCD-swizzled grid.
// Outputs: q,k MFMA-frag-packed uint4; v D-frag uint2.
__global__ __launch_bounds__(256) void qkv_kernel(
    const unsigned short* __restrict__ xb2, const float* __restrict__ b1,
    const uint4* __restrict__ w1t, unsigned short* __restrict__ qkvb)
{
  __shared__ __align__(16) uint4 wb4[2304];                 // 36864 B
  __shared__ __align__(16) unsigned short bn[4][2][16][38]; //  9728 B
  const int tid = threadIdx.x, wv = tid >> 6, lane = tid & 63;
  const int l15 = lane & 15, g = lane >> 4;
  // XCD swizzle: each XCD gets 90 contiguous mt's; the 6 same-mt blocks
  // land on one XCD (A-tile L2 reuse). 4320 = 8 XCD * 540.
  const int b = blockIdx.x;
  const int lid = (b & 7) * 540 + (b >> 3);
  const int mt = lid / 6, ch = lid - mt * 6;
  const int r0 = mt * 128;

  {
    const uint4* wsrc = w1t + (size_t)ch * 2304;
    #pragma unroll 1
    for (int i = tid; i < 2304; i += 256) wb4[i] = wsrc[i];
  }
  bf16x8 xa[2][6];
  {
    const uint4* asrc = (const uint4*)xb2;
    const int rt0 = mt * 8 + 2 * wv;
    #pragma unroll
    for (int rt = 0; rt < 2; ++rt)
      #pragma unroll
      for (int kk = 0; kk < 6; ++kk)
        xa[rt][kk] = __builtin_bit_cast(bf16x8,
            asrc[((size_t)(rt0 + rt) * 6 + kk) * 64 + lane]);
  }
  __syncthreads();
  const int mat = ch >> 1;
  const float bscale = (mat == 0) ? C_FOLD : 1.0f;
  #pragma unroll 1
  for (int hh = 0; hh < 3; ++hh) {
    const int h = (ch & 1) * 3 + hh;
    f32x4 acc[2][2];
    {
      float bv0 = b1[ch * 96 + hh * 32 + l15] * bscale;
      float bv1 = b1[ch * 96 + hh * 32 + 16 + l15] * bscale;
      #pragma unroll
      for (int rt = 0; rt < 2; ++rt) {
        acc[rt][0][0] = bv0; acc[rt][0][1] = bv0; acc[rt][0][2] = bv0; acc[rt][0][3] = bv0;
        acc[rt][1][0] = bv1; acc[rt][1][1] = bv1; acc[rt][1][2] = bv1; acc[rt][1][3] = bv1;
      }
    }
    #pragma unroll
    for (int kk = 0; kk < 6; ++kk) {
      bf16x8 b0  = __builtin_bit_cast(bf16x8, wb4[((2 * hh)     * 6 + kk) * 64 + lane]);
      bf16x8 b1f = __builtin_bit_cast(bf16x8, wb4[((2 * hh + 1) * 6 + kk) * 64 + lane]);
      acc[0][0] = MFMA16(xa[0][kk], b0, acc[0][0]);
      acc[0][1] = MFMA16(xa[0][kk], b1f, acc[0][1]);
      acc[1][0] = MFMA16(xa[1][kk], b0, acc[1][0]);
      acc[1][1] = MFMA16(xa[1][kk], b1f, acc[1][1]);
    }
    if (mat < 2) {
      // bounce to LDS (D layout) then read back as frags -> coalesced uint4
      #pragma unroll
      for (int rt = 0; rt < 2; ++rt)
        #pragma unroll
        for (int ct = 0; ct < 2; ++ct)
          #pragma unroll
          for (int j = 0; j < 4; ++j)
            bn[wv][rt][4 * g + j][16 * ct + l15] = cvtb(acc[rt][ct][j]);
      __builtin_amdgcn_s_waitcnt(0xC07F);  // lgkmcnt(0)
      #pragma unroll
      for (int rt = 0; rt < 2; ++rt) {
        const int row16 = r0 + 32 * wv + 16 * rt;
        const int win = row16 / 144, rg = (row16 - win * 144) >> 4;
        uint2 lo = *(const uint2*)(&bn[wv][rt][l15][4 * g]);
        uint2 hi = *(const uint2*)(&bn[wv][rt][l15][16 + 4 * g]);
        uint4 u; u.x = lo.x; u.y = lo.y; u.z = hi.x; u.w = hi.y;
        ((uint4*)qkvb)[((size_t)((mat * HEADS + h) * NWIN + win)) * 576 + rg * 64 + lane] = u;
      }
      __builtin_amdgcn_s_waitcnt(0xC07F);  // reads done before next hh rewrites bn
    } else {
      // V: D-frag-packed uint2 stores (decoded in attn)
      #pragma unroll
      for (int rt = 0; rt < 2; ++rt) {
        const int row16 = r0 + 32 * wv + 16 * rt;
        const int win = row16 / 144, rg = (row16 - win * 144) >> 4;
        uint2* dst = (uint2*)qkvb + ((size_t)((mat * HEADS + h) * NWIN + win)) * 1152
                     + (rg * 2) * 64 + lane;
        #pragma unroll
        for (int ct = 0; ct < 2; ++ct) dst[ct * 64] = pack4(acc[rt][ct]);
      }
    }
  }
}

// === attention per (window, head-triple): 9 waves, 3 heads, dbuf K/V ======
#define VT_LD 164
__global__ __launch_bounds__(576, 4) void attn6_kernel(
    const uint4* __restrict__ qf, const uint4* __restrict__ kf,
    const uint2* __restrict__ vf, const uint2* __restrict__ biasz,
    const unsigned long long* __restrict__ mq, unsigned short* __restrict__ xbuf)
{
  __shared__ __align__(16) uint4 ks[2][576];               // 18432 B
  __shared__ __align__(16) unsigned short vt[2][DH][VT_LD];// 20992 B
  const int tid = threadIdx.x, wv = tid >> 6, lane = tid & 63;
  const int l15 = lane & 15, g = lane >> 4;
  const int b = blockIdx.x, win = b >> 1, hg = b & 1, h0 = 3 * hg;
  const int wtype = win & (TW - 1);
  const int s = wv;                       // this wave's q-strip
  const int q = 16 * s + l15;
  const int m0 = h0 * NWIN + win;

  // loop-invariant: packed keep-nibbles (9 kst x 4 bits) for this (strip,lane)
  const unsigned long long mw = mq[((size_t)win * 9 + s) * 64 + lane];

  // prologue: stage head h0 into buffer 0; zero V pad cols for both buffers
  {
    ks[0][tid] = kf[(size_t)m0 * 576 + tid];
    const uint2* vs = vf + (size_t)m0 * 1152;
    #pragma unroll
    for (int t = 0; t < 2; ++t) {
      int i = tid + t * 576;
      int fid = i >> 6, ln = i & 63;
      int tok = 16 * (fid >> 1) + 4 * (ln >> 4);
      int d = 16 * (fid & 1) + (ln & 15);
      *(uint2*)(&vt[0][d][tok]) = vs[i];
    }
    #pragma unroll 1
    for (int i = tid; i < 2 * DH * 10; i += 576) {   // cols 144..163 := 0
      int buf = i / 320, rem = i - buf * 320;
      int r = rem / 10, c = 144 + (rem - r * 10) * 2;
      *(unsigned*)(&vt[buf][r][c]) = 0;
    }
  }
  __syncthreads();

  #pragma unroll 1
  for (int hh = 0; hh < 3; ++hh) {
    const int cur = hh & 1;
    const int h = h0 + hh;
    const int m = m0 + hh * NWIN;
    // per-head loads, issued up front (consumed after other waves progress)
    uint2 bb[9];
    {
      const uint2* bz = biasz + (((size_t)(wtype * HEADS + h) * 9 + s) * 9) * 64 + lane;
      #pragma unroll
      for (int kst = 0; kst < 9; ++kst) bb[kst] = bz[kst * 64];
    }
    const bf16x8 bq = __builtin_bit_cast(bf16x8, qf[(size_t)m * 576 + s * 64 + lane]);
    // prefetch next head's K/V into registers (LDS write deferred past compute)
    uint4 kreg;
    uint2 vr0, vr1;
    if (hh < 2) {
      kreg = kf[(size_t)(m + NWIN) * 576 + tid];
      const uint2* vs = vf + (size_t)(m + NWIN) * 1152;
      vr0 = vs[tid];
      vr1 = vs[tid + 576];
    }
    // ---- S^T = K Q^T + bias (C-operand); exp2; keep-mask; unnormalized P ----
    float sum = 0.f;
    uint4 pb[5];
    uint2 lo_pk;
    #pragma unroll
    for (int kst = 0; kst < 9; ++kst) {
      f32x4 c;
      c[0] = __uint_as_float(bb[kst].x << 16);
      c[1] = __uint_as_float(bb[kst].x & 0xffff0000u);
      c[2] = __uint_as_float(bb[kst].y << 16);
      c[3] = __uint_as_float(bb[kst].y & 0xffff0000u);
      f32x4 sv = MFMA16(__builtin_bit_cast(bf16x8, ks[cur][kst * 64 + lane]), bq, c);
      const unsigned nib = (unsigned)(mw >> (4 * kst)) & 0xFu;
      #pragma unroll
      for (int j = 0; j < 4; ++j) {
        float p = __builtin_amdgcn_exp2f(sv[j]);
        int keep = ((int)(nib << (31 - j))) >> 31;     // all-ones when keep
        p = __uint_as_float(__float_as_uint(p) & (unsigned)keep);
        sv[j] = p;
        sum += p;
      }
      uint2 pk = pack4(sv);
      if (kst & 1) {
        pb[kst >> 1].x = lo_pk.x; pb[kst >> 1].y = lo_pk.y;
        pb[kst >> 1].z = pk.x;    pb[kst >> 1].w = pk.y;
      } else {
        lo_pk = pk;
      }
    }
    pb[4].x = lo_pk.x; pb[4].y = lo_pk.y; pb[4].z = 0; pb[4].w = 0;
    sum += __shfl_xor(sum, 16);
    sum += __shfl_xor(sum, 32);
    const float inv = 1.f / sum;
    // ---- O^T = V^T P^T, normalize at store; scrambled xbuf layout ----
    const int r = q / 6, cb = (q - r * 6) * DH;
    unsigned short* xrow = xbuf + (size_t)(24 * m + r) * DIM + cb + 4 * g;
    #pragma unroll
    for (int dt = 0; dt < 2; ++dt) {
      const unsigned short* vrow = &vt[cur][dt * 16 + l15][4 * g];
      f32x4 ot; ot[0] = 0.f; ot[1] = 0.f; ot[2] = 0.f; ot[3] = 0.f;
      #pragma unroll
      for (int s5 = 0; s5 < 5; ++s5)
        ot = MFMA16(ld_frag(vrow + s5 * 32), __builtin_bit_cast(bf16x8, pb[s5]), ot);
      ot[0] *= inv; ot[1] *= inv; ot[2] *= inv; ot[3] *= inv;
      *(uint2*)(xrow + dt * 16) = pack4(ot);
    }
    // ---- stage next head into the alternate buffer, then one barrier ----
    if (hh < 2) {
      ks[cur ^ 1][tid] = kreg;
      #pragma unroll
      for (int t = 0; t < 2; ++t) {
        int i = tid + t * 576;
        int fid = i >> 6, ln = i & 63;
        int tok = 16 * (fid >> 1) + 4 * (ln >> 4);
        int d = 16 * (fid & 1) + (ln & 15);
        *(uint2*)(&vt[cur ^ 1][d][tok]) = (t == 0) ? vr0 : vr1;
      }
    }
    __syncthreads();
  }
}

// ============ out projection: xbuf(92160x192 bf16) @ w2 + b2 ==============
// Two 96-col chunks (36.9 KB LDS -> 4 blocks/CU).
__global__ __launch_bounds__(512) void proj_kernel(
    const unsigned short* __restrict__ xbuf, const uint4* __restrict__ w2t,
    const float* __restrict__ b2, float* __restrict__ out)
{
  __shared__ __align__(16) uint4 wb4[2304];  // 36864 B (one 96-col chunk)
  const int tid = threadIdx.x, wv = tid >> 6, lane = tid & 63;
  const int l15 = lane & 15, g = lane >> 4;
  const int r0 = blockIdx.x * 128;
  bf16x8 xa[6];
  {
    const unsigned short* xrow = xbuf + (size_t)(r0 + 16 * wv + l15) * DIM;
    #pragma unroll
    for (int kk = 0; kk < 6; ++kk) xa[kk] = ld_frag(xrow + kk * 32 + 4 * g);
  }
  #pragma unroll 1
  for (int ch = 0; ch < 2; ++ch) {
    __syncthreads();
    {
      const uint4* wsrc = w2t + (size_t)ch * 2304;
      #pragma unroll 1
      for (int i = tid; i < 2304; i += 512) wb4[i] = wsrc[i];
    }
    __syncthreads();
    #pragma unroll 1
    for (int nt = 0; nt < 6; ++nt) {
      const int n = ch * 96 + nt * 16 + l15;
      float bv = b2[n];
      f32x4 acc; acc[0] = bv; acc[1] = bv; acc[2] = bv; acc[3] = bv;
      #pragma unroll
      for (int kk = 0; kk < 6; ++kk)
        acc = MFMA16(xa[kk], __builtin_bit_cast(bf16x8, wb4[(nt * 6 + kk) * 64 + lane]), acc);
      #pragma unroll
      for (int j = 0; j < 4; ++j)
        out[(size_t)(r0 + 16 * wv + 4 * g + j) * DIM + n] = acc[j];
    }
  }
}

extern "C" void kernel_launch(void* const* d_in, const int* in_sizes, int n_in,
                              void* d_out, int out_size, void* d_ws, size_t ws_size,
                              hipStream_t stream)
{
  const float* x     = (const float*)d_in[0];
  const float* mask  = (const float*)d_in[1];
  const float* w1    = (const float*)d_in[2];
  const float* b1    = (const float*)d_in[3];
  const float* w2    = (const float*)d_in[4];
  const float* b2    = (const float*)d_in[5];
  const float* table = (const float*)d_in[6];
  const int*   pidx  = (const int*)d_in[7];
  float* out = (float*)d_out;
  unsigned char* ws = (unsigned char*)d_ws;
  // ws: w1t 221184 | w2t 73728 | biasz 15925248 | mq 2949120 |
  //     qkvb 106168320 (q-frag | k-frag | v D-frag) |
  //     xbuf 35389440 (xb2 aliases; dead before attn6 writes) -> 171,048,960 B
  uint4* w1t            = (uint4*)(ws);
  uint4* w2t            = (uint4*)(ws + 221184);
  uint2* biasz          = (uint2*)(ws + 294912);
  unsigned long long* mq = (unsigned long long*)(ws + 16220160);
  unsigned short* qkvb  = (unsigned short*)(ws + 29491200);
  unsigned short* xbuf  = (unsigned short*)(ws + 135659520);
  unsigned short* xb2   = xbuf;   // alias: consumed by qkv before attn6 writes

  const uint4* qf = (const uint4*)qkvb;
  const uint4* kf = (const uint4*)(ws + 29491200 + 35389440);
  const uint2* vf = (const uint2*)(ws + 29491200 + 70778880);

  megaprep  <<<dim3(4222), dim3(256), 0, stream>>>(x, mask, w1, w2, table, pidx,
                                                   xb2, mq, w1t, w2t, biasz);
  qkv_kernel<<<dim3(4320), dim3(256), 0, stream>>>(xb2, b1, w1t, qkvb);
  attn6_kernel<<<dim3(1280), dim3(576), 0, stream>>>(qf, kf, vf, biasz, mq, xbuf);
  proj_kernel<<<dim3(720), dim3(512), 0, stream>>>(xbuf, w2t, b2, out);
}